// Round 4
// baseline (239.472 us; speedup 1.0000x reference)
//
#include <hip/hip_runtime.h>
#include <math.h>

// BIMM2D: M=250000 points, P=4 interior phases, K=6 interface pairs, N_MC=64
#define KN 384            // K * N_MC table entries
#define TPB 256
#define PTS_PER_WAVE 32
#define PTS_PER_BLOCK 128 // 4 waves * 32

typedef float v2f __attribute__((ext_vector_type(2)));

// Device-global scratch. g_ctr is module-init 0 and self-restored by the last
// block each launch -> graph-replay safe, independent of d_ws poison.
__device__ double g_part[2048];
__device__ int    g_ctr = 0;

__device__ __forceinline__ float fexp2(float x) {
  return __builtin_amdgcn_exp2f(x);   // native v_exp_f32
}

// Decomposition (R4): table entries live in REGISTERS (lane l owns entries
// g*64+l, g=0..5 -> all 384 entries per wave in 18 VGPR); points are
// BROADCAST from LDS via uniform ds_read_b64 (one per point, vs per-entry
// b128 reads in R1-R3). 8 points batched per iteration -> 96 independent
// exps in flight; 6-stage shfl_xor butterfly gives every lane the full
// 384-entry sum (bit-identical in all lanes -> exact /64 at the end).
__global__ __launch_bounds__(TPB, 8) void fused_kernel(
    const float* __restrict__ u, const float* __restrict__ v,
    const float* __restrict__ eps, const float* __restrict__ I,
    const float* __restrict__ W, const float* __restrict__ sb_,
    const float* __restrict__ sn_, const float* __restrict__ d_,
    const float* __restrict__ r_, float* __restrict__ out,
    int M, int nb) {
  __shared__ float4 stab[KN];
  __shared__ float4 spts[PTS_PER_BLOCK];
  __shared__ double red[TPB];
  __shared__ int    slast;
  const int tid  = threadIdx.x;
  const int lane = tid & 63;
  const int wid  = tid >> 6;

  // ---- folded constants (uniform; float, faithful to f32 reference) ----
  const float sb  = sb_[0];
  const float sn  = sn_[0];
  const float dd  = d_[0];
  const float rho = tanhf(r_[0]);
  const float s2  = sn * sn * (1.f - rho);      // sr^2
  const float sr  = sqrtf(s2);
  const float isn = 1.f / sn;
  const float inv_s2 = 1.f / s2;
  const float LOG2E = 1.4426950408889634f;
  const float SQH   = sqrtf(0.5f * LOG2E);      // sqrt(0.5*log2 e)

  float wmax = W[0];
  for (int j = 1; j < 10; ++j) wmax = fmaxf(wmax, W[j]);
  float se = 0.f;
  for (int j = 0; j < 10; ++j) se += expf(W[j] - wmax);
  const float lse = wmax + logf(se);

  const float LOG2PI_ = 1.8378770664093453f;
  const float LOG2_   = 0.6931471805599453f;
  const float LGG32   = -0.12078223763524522f;  // log(gamma(1.5))
  const float LOGPI_  = 1.1447298858494002f;
  const float Cterm = -logf(sn) - 0.5f * LOG2PI_ - logf(sr) - 0.5f * LOGPI_;
  const float Cint0 = LOG2_ - LGG32 - 3.f * logf(sr) - logf(sn) - 0.5f * LOG2PI_;

  float wint[4], cq[4];
#pragma unroll
  for (int p = 0; p < 4; ++p) {
    wint[p] = expf(W[p] - lse + Cint0);
    cq[p]   = I[p] * isn * SQH;
  }

  // ---- per-(k,n) table into LDS (exp2-folded) ----
  // stab[t] = { In/sn*SQH, (2G/s2)*log2e, wk*exp(-G^2/s2)/G, 0 }
  const int IAc[6] = {0, 0, 0, 1, 1, 2};
  const int IBc[6] = {1, 2, 3, 2, 3, 3};
  for (int t = tid; t < KN; t += TPB) {
    const int k = t >> 6;
    const float Ia = I[IAc[k]], Ib = I[IBc[k]];
    const float wk = expf(W[4 + k] - lse + Cterm) * (1.0f / 64.0f);
    const float e  = eps[t];
    const float x  = e * 2.f * dd * sb - dd * sb;
    const float y  = x / (1.4142135623730951f * sb);
    const float In = (erff(y) + 1.f) * 0.5f * (Ib - Ia) + Ia;
    const float qq = 2.f * (In - Ia) / (Ib - Ia) - 1.f;
    const float gi = erfinvf(qq);
    const float G  = (Ib - Ia) * 0.3989422804014327f / sb * expf(-gi * gi);
    float4 tt;
    tt.x = In * isn * SQH;
    tt.y = 2.f * inv_s2 * G * LOG2E;
    tt.z = wk * expf(-G * G * inv_s2) / G;
    tt.w = 0.f;
    stab[t] = tt;
  }

  // ---- point staging: per-point (us', vv, c0, c1); pad -> (0,0,0,1) ----
  // acc(point) = c1 + c0 * S,  S = sum over 384 entries of tz*(e1-e2)
  // c0 = v*g, c1 = v^2*g*aint, g = exp(-v^2/s2)
  if (tid < PTS_PER_BLOCK) {
    const int idx = blockIdx.x * PTS_PER_BLOCK + tid;
    float4 pd = {0.f, 0.f, 0.f, 1.f};
    if (idx < M) {
      const float uu = u[idx], vv = v[idx];
      const float usq = uu * isn * SQH;
      const float gg = fexp2(-vv * vv * inv_s2 * LOG2E);
      float aint = 0.f;
#pragma unroll
      for (int p = 0; p < 4; ++p) {
        const float dq = usq - cq[p];
        aint = fmaf(wint[p], fexp2(-dq * dq), aint);
      }
      pd.x = usq;
      pd.y = vv;
      pd.z = vv * gg;
      pd.w = vv * vv * gg * aint;
    }
    spts[tid] = pd;
  }
  __syncthreads();

  // ---- gather this lane's 6 table entries into registers ----
  float tx[6], ty[6], tz[6];
#pragma unroll
  for (int g = 0; g < 6; ++g) {
    const float4 t4 = stab[(g << 6) | lane];
    tx[g] = t4.x; ty[g] = t4.y; tz[g] = t4.z;
  }

  // ---- main loop: 4 batches of 8 points per wave ----
  const float* wp = (const float*)(spts + wid * PTS_PER_WAVE);
  double lsum = 0.0;
  for (int b = 0; b < PTS_PER_WAVE; b += 8) {
    float S[8];
#pragma unroll
    for (int half = 0; half < 2; ++half) {
      const int pb = b + half * 4;
      // uniform ds_read_b64 of (us', vv) for 4 points
      v2f uv0 = *(const v2f*)(wp + 4 * (pb + 0));
      v2f uv1 = *(const v2f*)(wp + 4 * (pb + 1));
      v2f uv2 = *(const v2f*)(wp + 4 * (pb + 2));
      v2f uv3 = *(const v2f*)(wp + 4 * (pb + 3));
      const v2f us01 = {uv0.x, uv1.x}, vv01 = {uv0.y, uv1.y};
      const v2f us23 = {uv2.x, uv3.x}, vv23 = {uv2.y, uv3.y};
      v2f S01 = {0.f, 0.f}, S23 = {0.f, 0.f};
#pragma unroll
      for (int g = 0; g < 6; ++g) {
        const float txg = tx[g], tyg = ty[g], tzg = tz[g];
        {
          const v2f zp = vv01 * tyg;
          const v2f du = us01 - txg;
          const v2f a1 = __builtin_elementwise_fma(du, -du, zp);   //  z'-h'
          const v2f a2 = __builtin_elementwise_fma((v2f)(-2.f), zp, a1); // -z'-h'
          v2f ed;
          ed.x = fexp2(a1.x) - fexp2(a2.x);
          ed.y = fexp2(a1.y) - fexp2(a2.y);
          S01 = __builtin_elementwise_fma(ed, (v2f)(tzg), S01);
        }
        {
          const v2f zp = vv23 * tyg;
          const v2f du = us23 - txg;
          const v2f a1 = __builtin_elementwise_fma(du, -du, zp);
          const v2f a2 = __builtin_elementwise_fma((v2f)(-2.f), zp, a1);
          v2f ed;
          ed.x = fexp2(a1.x) - fexp2(a2.x);
          ed.y = fexp2(a1.y) - fexp2(a2.y);
          S23 = __builtin_elementwise_fma(ed, (v2f)(tzg), S23);
        }
      }
      S[half * 4 + 0] = S01.x; S[half * 4 + 1] = S01.y;
      S[half * 4 + 2] = S23.x; S[half * 4 + 3] = S23.y;
    }

    // 6-stage butterfly over 64 lanes; all lanes end bit-identical
#pragma unroll
    for (int st = 0; st < 6; ++st) {
      const int m = 1 << st;
#pragma unroll
      for (int j = 0; j < 8; ++j) S[j] += __shfl_xor(S[j], m, 64);
    }

    // epilogue (uniform across lanes): acc = c1 + c0*S, accumulate log
#pragma unroll
    for (int j = 0; j < 8; ++j) {
      const v2f cc = *(const v2f*)(wp + 4 * (b + j) + 2);  // {c0, c1}
      lsum += (double)__logf(fmaf(cc.x, S[j], cc.y));
    }
  }

  // ---- block reduction (every lane of a wave holds identical lsum; the
  //      tree sums 64 identical copies exactly -> divide by 64 at the end) ----
  red[tid] = lsum;
  __syncthreads();
  for (int s = TPB / 2; s > 0; s >>= 1) {
    if (tid < s) red[tid] += red[tid + s];
    __syncthreads();
  }
  if (tid == 0)
    __hip_atomic_store(&g_part[blockIdx.x], red[0], __ATOMIC_RELAXED,
                       __HIP_MEMORY_SCOPE_AGENT);

  // ---- last-block-done final reduction (fixed order -> deterministic) ----
  if (tid == 0) {
    const int c = __hip_atomic_fetch_add(&g_ctr, 1, __ATOMIC_ACQ_REL,
                                         __HIP_MEMORY_SCOPE_AGENT);
    slast = (c == nb - 1) ? 1 : 0;
  }
  __syncthreads();
  if (slast) {
    double s = 0.0;
    for (int j = tid; j < nb; j += TPB)
      s += __hip_atomic_load(&g_part[j], __ATOMIC_RELAXED,
                             __HIP_MEMORY_SCOPE_AGENT);
    red[tid] = s;
    __syncthreads();
    for (int k2 = TPB / 2; k2 > 0; k2 >>= 1) {
      if (tid < k2) red[tid] += red[tid + k2];
      __syncthreads();
    }
    if (tid == 0) {
      out[0] = (float)(-red[0] / (64.0 * (double)M));
      __hip_atomic_store(&g_ctr, 0, __ATOMIC_RELAXED,
                         __HIP_MEMORY_SCOPE_AGENT);  // restore for next replay
    }
  }
}

extern "C" void kernel_launch(void* const* d_in, const int* in_sizes, int n_in,
                              void* d_out, int out_size, void* d_ws, size_t ws_size,
                              hipStream_t stream) {
  const float* u   = (const float*)d_in[0];
  const float* v   = (const float*)d_in[1];
  const float* eps = (const float*)d_in[2];
  const float* I   = (const float*)d_in[3];
  const float* W   = (const float*)d_in[4];
  const float* sb  = (const float*)d_in[5];
  const float* sn  = (const float*)d_in[6];
  const float* dd  = (const float*)d_in[7];
  const float* r   = (const float*)d_in[8];
  const int M  = in_sizes[0];
  const int nb = (M + PTS_PER_BLOCK - 1) / PTS_PER_BLOCK;  // 1954 <= 2048
  hipLaunchKernelGGL(fused_kernel, dim3(nb), dim3(TPB), 0, stream,
                     u, v, eps, I, W, sb, sn, dd, r, (float*)d_out, M, nb);
}

// Round 6
// 122.290 us; speedup vs baseline: 1.9582x; 1.9582x over previous
//
#include <hip/hip_runtime.h>
#include <math.h>

// BIMM2D: M=250000 points, P=4 interior phases, K=6 interface pairs, N_MC=64
#define KN 384            // K * N_MC table entries
#define TPB 256
#define PTS_PER_WAVE 32
#define PTS_PER_BLOCK 128 // 4 waves * 32

typedef float v2f __attribute__((ext_vector_type(2)));

// Device-global scratch. g_ctr is module-init 0 and self-restored by the last
// block each launch -> graph-replay safe, independent of d_ws poison.
__device__ double g_part[2048];
__device__ int    g_ctr = 0;

__device__ __forceinline__ float fexp2(float x) {
  return __builtin_amdgcn_exp2f(x);   // native v_exp_f32
}

// Decomposition (R4 concept, R5 fix): table entries live in REGISTERS (lane l
// owns entries g*64+l, g=0..5 -> all 384 entries per wave in 18 VGPR); points
// are BROADCAST from LDS via uniform ds_read (one per point). 8 points batched
// per iteration -> 96 independent exps in flight; 6-stage shfl_xor butterfly
// gives every lane the full 384-entry sum (bit-identical in all lanes).
// R5: launch_bounds min-waves 8 -> 4. R4's 64-VGPR cap spilled the table and
// S[] to scratch (236MB fetch/disp, VALUBusy 20%). 128-VGPR budget holds the
// ~90-reg live set with zero spill.
__global__ __launch_bounds__(TPB, 4) void fused_kernel(
    const float* __restrict__ u, const float* __restrict__ v,
    const float* __restrict__ eps, const float* __restrict__ I,
    const float* __restrict__ W, const float* __restrict__ sb_,
    const float* __restrict__ sn_, const float* __restrict__ d_,
    const float* __restrict__ r_, float* __restrict__ out,
    int M, int nb) {
  __shared__ float4 stab[KN];
  __shared__ float4 spts[PTS_PER_BLOCK];
  __shared__ double red[TPB];
  __shared__ int    slast;
  const int tid  = threadIdx.x;
  const int lane = tid & 63;
  const int wid  = tid >> 6;

  // ---- folded constants (uniform; float, faithful to f32 reference) ----
  const float sb  = sb_[0];
  const float sn  = sn_[0];
  const float dd  = d_[0];
  const float rho = tanhf(r_[0]);
  const float s2  = sn * sn * (1.f - rho);      // sr^2
  const float sr  = sqrtf(s2);
  const float isn = 1.f / sn;
  const float inv_s2 = 1.f / s2;
  const float LOG2E = 1.4426950408889634f;
  const float SQH   = sqrtf(0.5f * LOG2E);      // sqrt(0.5*log2 e)

  float wmax = W[0];
  for (int j = 1; j < 10; ++j) wmax = fmaxf(wmax, W[j]);
  float se = 0.f;
  for (int j = 0; j < 10; ++j) se += expf(W[j] - wmax);
  const float lse = wmax + logf(se);

  const float LOG2PI_ = 1.8378770664093453f;
  const float LOG2_   = 0.6931471805599453f;
  const float LGG32   = -0.12078223763524522f;  // log(gamma(1.5))
  const float LOGPI_  = 1.1447298858494002f;
  const float Cterm = -logf(sn) - 0.5f * LOG2PI_ - logf(sr) - 0.5f * LOGPI_;
  const float Cint0 = LOG2_ - LGG32 - 3.f * logf(sr) - logf(sn) - 0.5f * LOG2PI_;

  float wint[4], cq[4];
#pragma unroll
  for (int p = 0; p < 4; ++p) {
    wint[p] = expf(W[p] - lse + Cint0);
    cq[p]   = I[p] * isn * SQH;
  }

  // ---- per-(k,n) table into LDS (exp2-folded) ----
  // stab[t] = { In/sn*SQH, (2G/s2)*log2e, wk*exp(-G^2/s2)/G, 0 }
  const int IAc[6] = {0, 0, 0, 1, 1, 2};
  const int IBc[6] = {1, 2, 3, 2, 3, 3};
  for (int t = tid; t < KN; t += TPB) {
    const int k = t >> 6;
    const float Ia = I[IAc[k]], Ib = I[IBc[k]];
    const float wk = expf(W[4 + k] - lse + Cterm) * (1.0f / 64.0f);
    const float e  = eps[t];
    const float x  = e * 2.f * dd * sb - dd * sb;
    const float y  = x / (1.4142135623730951f * sb);
    const float In = (erff(y) + 1.f) * 0.5f * (Ib - Ia) + Ia;
    const float qq = 2.f * (In - Ia) / (Ib - Ia) - 1.f;
    const float gi = erfinvf(qq);
    const float G  = (Ib - Ia) * 0.3989422804014327f / sb * expf(-gi * gi);
    float4 tt;
    tt.x = In * isn * SQH;
    tt.y = 2.f * inv_s2 * G * LOG2E;
    tt.z = wk * expf(-G * G * inv_s2) / G;
    tt.w = 0.f;
    stab[t] = tt;
  }

  // ---- point staging: per-point (us', vv, c0, c1); pad -> (0,0,0,1) ----
  // acc(point) = c1 + c0 * S,  S = sum over 384 entries of tz*(e1-e2)
  // c0 = v*g, c1 = v^2*g*aint, g = exp(-v^2/s2)
  if (tid < PTS_PER_BLOCK) {
    const int idx = blockIdx.x * PTS_PER_BLOCK + tid;
    float4 pd = {0.f, 0.f, 0.f, 1.f};
    if (idx < M) {
      const float uu = u[idx], vv = v[idx];
      const float usq = uu * isn * SQH;
      const float gg = fexp2(-vv * vv * inv_s2 * LOG2E);
      float aint = 0.f;
#pragma unroll
      for (int p = 0; p < 4; ++p) {
        const float dq = usq - cq[p];
        aint = fmaf(wint[p], fexp2(-dq * dq), aint);
      }
      pd.x = usq;
      pd.y = vv;
      pd.z = vv * gg;
      pd.w = vv * vv * gg * aint;
    }
    spts[tid] = pd;
  }
  __syncthreads();

  // ---- gather this lane's 6 table entries into registers ----
  float tx[6], ty[6], tz[6];
#pragma unroll
  for (int g = 0; g < 6; ++g) {
    const float4 t4 = stab[(g << 6) | lane];
    tx[g] = t4.x; ty[g] = t4.y; tz[g] = t4.z;
  }

  // ---- main loop: 4 batches of 8 points per wave ----
  const float* wp = (const float*)(spts + wid * PTS_PER_WAVE);
  double lsum = 0.0;
  for (int b = 0; b < PTS_PER_WAVE; b += 8) {
    float S[8];
#pragma unroll
    for (int half = 0; half < 2; ++half) {
      const int pb = b + half * 4;
      // uniform ds_read of (us', vv) for 4 points
      v2f uv0 = *(const v2f*)(wp + 4 * (pb + 0));
      v2f uv1 = *(const v2f*)(wp + 4 * (pb + 1));
      v2f uv2 = *(const v2f*)(wp + 4 * (pb + 2));
      v2f uv3 = *(const v2f*)(wp + 4 * (pb + 3));
      const v2f us01 = {uv0.x, uv1.x}, vv01 = {uv0.y, uv1.y};
      const v2f us23 = {uv2.x, uv3.x}, vv23 = {uv2.y, uv3.y};
      v2f S01 = {0.f, 0.f}, S23 = {0.f, 0.f};
#pragma unroll
      for (int g = 0; g < 6; ++g) {
        const float txg = tx[g], tyg = ty[g], tzg = tz[g];
        {
          const v2f zp = vv01 * tyg;
          const v2f du = us01 - txg;
          const v2f a1 = __builtin_elementwise_fma(du, -du, zp);        //  z'-h'
          const v2f a2 = __builtin_elementwise_fma((v2f)(-2.f), zp, a1); // -z'-h'
          v2f ed;
          ed.x = fexp2(a1.x) - fexp2(a2.x);
          ed.y = fexp2(a1.y) - fexp2(a2.y);
          S01 = __builtin_elementwise_fma(ed, (v2f)(tzg), S01);
        }
        {
          const v2f zp = vv23 * tyg;
          const v2f du = us23 - txg;
          const v2f a1 = __builtin_elementwise_fma(du, -du, zp);
          const v2f a2 = __builtin_elementwise_fma((v2f)(-2.f), zp, a1);
          v2f ed;
          ed.x = fexp2(a1.x) - fexp2(a2.x);
          ed.y = fexp2(a1.y) - fexp2(a2.y);
          S23 = __builtin_elementwise_fma(ed, (v2f)(tzg), S23);
        }
      }
      S[half * 4 + 0] = S01.x; S[half * 4 + 1] = S01.y;
      S[half * 4 + 2] = S23.x; S[half * 4 + 3] = S23.y;
    }

    // 6-stage butterfly over 64 lanes; all lanes end bit-identical
#pragma unroll
    for (int st = 0; st < 6; ++st) {
      const int m = 1 << st;
#pragma unroll
      for (int j = 0; j < 8; ++j) S[j] += __shfl_xor(S[j], m, 64);
    }

    // epilogue (uniform across lanes): acc = c1 + c0*S, accumulate log
#pragma unroll
    for (int j = 0; j < 8; ++j) {
      const v2f cc = *(const v2f*)(wp + 4 * (b + j) + 2);  // {c0, c1}
      lsum += (double)__logf(fmaf(cc.x, S[j], cc.y));
    }
  }

  // ---- block reduction (all 64 lanes of a wave hold identical lsum; the
  //      tree sums 64 identical copies exactly -> divide by 64 at the end) ----
  red[tid] = lsum;
  __syncthreads();
  for (int s = TPB / 2; s > 0; s >>= 1) {
    if (tid < s) red[tid] += red[tid + s];
    __syncthreads();
  }
  if (tid == 0)
    __hip_atomic_store(&g_part[blockIdx.x], red[0], __ATOMIC_RELAXED,
                       __HIP_MEMORY_SCOPE_AGENT);

  // ---- last-block-done final reduction (fixed order -> deterministic) ----
  if (tid == 0) {
    const int c = __hip_atomic_fetch_add(&g_ctr, 1, __ATOMIC_ACQ_REL,
                                         __HIP_MEMORY_SCOPE_AGENT);
    slast = (c == nb - 1) ? 1 : 0;
  }
  __syncthreads();
  if (slast) {
    double s = 0.0;
    for (int j = tid; j < nb; j += TPB)
      s += __hip_atomic_load(&g_part[j], __ATOMIC_RELAXED,
                             __HIP_MEMORY_SCOPE_AGENT);
    red[tid] = s;
    __syncthreads();
    for (int k2 = TPB / 2; k2 > 0; k2 >>= 1) {
      if (tid < k2) red[tid] += red[tid + k2];
      __syncthreads();
    }
    if (tid == 0) {
      out[0] = (float)(-red[0] / (64.0 * (double)M));
      __hip_atomic_store(&g_ctr, 0, __ATOMIC_RELAXED,
                         __HIP_MEMORY_SCOPE_AGENT);  // restore for next replay
    }
  }
}

extern "C" void kernel_launch(void* const* d_in, const int* in_sizes, int n_in,
                              void* d_out, int out_size, void* d_ws, size_t ws_size,
                              hipStream_t stream) {
  const float* u   = (const float*)d_in[0];
  const float* v   = (const float*)d_in[1];
  const float* eps = (const float*)d_in[2];
  const float* I   = (const float*)d_in[3];
  const float* W   = (const float*)d_in[4];
  const float* sb  = (const float*)d_in[5];
  const float* sn  = (const float*)d_in[6];
  const float* dd  = (const float*)d_in[7];
  const float* r   = (const float*)d_in[8];
  const int M  = in_sizes[0];
  const int nb = (M + PTS_PER_BLOCK - 1) / PTS_PER_BLOCK;  // 1954 <= 2048
  hipLaunchKernelGGL(fused_kernel, dim3(nb), dim3(TPB), 0, stream,
                     u, v, eps, I, W, sb, sn, dd, r, (float*)d_out, M, nb);
}

// Round 10
// 106.642 us; speedup vs baseline: 2.2456x; 1.1467x over previous
//
#include <hip/hip_runtime.h>
#include <math.h>

// BIMM2D: M=250000 points, P=4 interior phases, K=6 interface pairs, N_MC=64
#define KN 384            // K * N_MC table entries
#define TPB 256

// Device-global scratch. g_ctr is module-init 0 and self-restored by the last
// block each launch -> graph-replay safe, independent of d_ws poison.
__device__ double g_part[1024];
__device__ int    g_ctr = 0;

__device__ __forceinline__ float fexp2(float x) {
  return __builtin_amdgcn_exp2f(x);   // native v_exp_f32
}

// R7 structure (from R1/R3/R6 cost triangulation):
//  - 1 point/thread, 977 blocks -> ~15 waves/CU resident for latency hiding.
//  - table in LDS as SoA (stx/sty/stz); inner loop reads 3 wave-uniform
//    float4 broadcasts per 4 entries (single address per wave = cheapest LDS
//    mode, 0.75 reads/entry vs 1.0 in R1, vs per-lane b128 in R3).
//  - no point staging, no shfl butterfly (R6's serial 6-stage chain killed it).
//  - per entry: du, -du^2, a1=fma(v,ty,nd), a2=fma(v,-ty,nd), 2 exp2,
//    2 accum-fma = 6 VALU + 2 trans; 4 independent accumulators.
__global__ __launch_bounds__(TPB, 4) void fused_kernel(
    const float* __restrict__ u, const float* __restrict__ v,
    const float* __restrict__ eps, const float* __restrict__ I,
    const float* __restrict__ W, const float* __restrict__ sb_,
    const float* __restrict__ sn_, const float* __restrict__ d_,
    const float* __restrict__ r_, float* __restrict__ out,
    int M, int nb) {
  __shared__ float stx[KN], sty[KN], stz[KN];
  __shared__ double red[TPB];
  __shared__ int    slast;
  const int tid = threadIdx.x;
  const int i   = blockIdx.x * TPB + tid;

  // hoist point load to overlap with the prelude
  float uu = 0.f, vv = 1.f;
  if (i < M) { uu = u[i]; vv = v[i]; }

  // ---- folded constants (uniform; float, faithful to f32 reference) ----
  const float sb  = sb_[0];
  const float sn  = sn_[0];
  const float dd  = d_[0];
  const float rho = tanhf(r_[0]);
  const float s2  = sn * sn * (1.f - rho);      // sr^2
  const float sr  = sqrtf(s2);
  const float isn = 1.f / sn;
  const float inv_s2 = 1.f / s2;
  const float LOG2E = 1.4426950408889634f;
  const float SQH   = sqrtf(0.5f * LOG2E);      // sqrt(0.5*log2 e)

  float wmax = W[0];
  for (int j = 1; j < 10; ++j) wmax = fmaxf(wmax, W[j]);
  float se = 0.f;
  for (int j = 0; j < 10; ++j) se += expf(W[j] - wmax);
  const float lse = wmax + logf(se);

  const float LOG2PI_ = 1.8378770664093453f;
  const float LOG2_   = 0.6931471805599453f;
  const float LGG32   = -0.12078223763524522f;  // log(gamma(1.5))
  const float LOGPI_  = 1.1447298858494002f;
  const float Cterm = -logf(sn) - 0.5f * LOG2PI_ - logf(sr) - 0.5f * LOGPI_;
  const float Cint0 = LOG2_ - LGG32 - 3.f * logf(sr) - logf(sn) - 0.5f * LOG2PI_;

  float wint[4], cq[4];
#pragma unroll
  for (int p = 0; p < 4; ++p) {
    wint[p] = expf(W[p] - lse + Cint0);
    cq[p]   = I[p] * isn * SQH;
  }

  // ---- per-(k,n) table into LDS (SoA, exp2-folded) ----
  // stx = In/sn*SQH, sty = (2G/s2)*log2e, stz = wk*exp(-G^2/s2)/G
  const int IAc[6] = {0, 0, 0, 1, 1, 2};
  const int IBc[6] = {1, 2, 3, 2, 3, 3};
  for (int t = tid; t < KN; t += TPB) {
    const int k = t >> 6;
    const float Ia = I[IAc[k]], Ib = I[IBc[k]];
    const float wk = expf(W[4 + k] - lse + Cterm) * (1.0f / 64.0f);
    const float e  = eps[t];
    const float x  = e * 2.f * dd * sb - dd * sb;
    const float y  = x / (1.4142135623730951f * sb);
    const float In = (erff(y) + 1.f) * 0.5f * (Ib - Ia) + Ia;
    const float qq = 2.f * (In - Ia) / (Ib - Ia) - 1.f;
    const float gi = erfinvf(qq);
    const float G  = (Ib - Ia) * 0.3989422804014327f / sb * expf(-gi * gi);
    stx[t] = In * isn * SQH;
    sty[t] = 2.f * inv_s2 * G * LOG2E;
    stz[t] = wk * expf(-G * G * inv_s2) / G;
  }

  // ---- per-thread point prelude ----
  // acc(point) = c1 + c0 * S,  S = sum over entries of tz*(e1-e2)
  // c0 = v*g, c1 = v^2*g*aint, g = exp(-v^2/s2); pad threads: c0=0, c1=1.
  const float us = uu * isn * SQH;
  const float gg = fexp2(-vv * vv * inv_s2 * LOG2E);
  float aint = 0.f;
#pragma unroll
  for (int p = 0; p < 4; ++p) {
    const float dq = us - cq[p];
    aint = fmaf(wint[p], fexp2(-dq * dq), aint);
  }
  const float c0 = (i < M) ? vv * gg : 0.f;
  const float c1 = (i < M) ? vv * vv * gg * aint : 1.f;

  __syncthreads();

  // ---- main loop: 384 entries, SoA uniform-broadcast float4 loads ----
  float S0 = 0.f, S1 = 0.f, S2 = 0.f, S3 = 0.f;
#pragma unroll 2
  for (int t = 0; t < KN; t += 4) {
    const float4 X = *(const float4*)(stx + t);
    const float4 Y = *(const float4*)(sty + t);
    const float4 Z = *(const float4*)(stz + t);
    {
      const float du = us - X.x, nd = du * -du;
      const float a1 = fmaf(vv, Y.x, nd), a2 = fmaf(vv, -Y.x, nd);
      S0 = fmaf(Z.x, fexp2(a1), S0);
      S0 = fmaf(-Z.x, fexp2(a2), S0);
    }
    {
      const float du = us - X.y, nd = du * -du;
      const float a1 = fmaf(vv, Y.y, nd), a2 = fmaf(vv, -Y.y, nd);
      S1 = fmaf(Z.y, fexp2(a1), S1);
      S1 = fmaf(-Z.y, fexp2(a2), S1);
    }
    {
      const float du = us - X.z, nd = du * -du;
      const float a1 = fmaf(vv, Y.z, nd), a2 = fmaf(vv, -Y.z, nd);
      S2 = fmaf(Z.z, fexp2(a1), S2);
      S2 = fmaf(-Z.z, fexp2(a2), S2);
    }
    {
      const float du = us - X.w, nd = du * -du;
      const float a1 = fmaf(vv, Y.w, nd), a2 = fmaf(vv, -Y.w, nd);
      S3 = fmaf(Z.w, fexp2(a1), S3);
      S3 = fmaf(-Z.w, fexp2(a2), S3);
    }
  }
  const float S = (S0 + S1) + (S2 + S3);

  // per-point log-likelihood (pad threads: log(1) = 0)
  double mysum = (double)__logf(fmaf(c0, S, c1));

  // ---- block reduction (deterministic tree) ----
  red[tid] = mysum;
  __syncthreads();
  for (int s = TPB / 2; s > 0; s >>= 1) {
    if (tid < s) red[tid] += red[tid + s];
    __syncthreads();
  }
  if (tid == 0)
    __hip_atomic_store(&g_part[blockIdx.x], red[0], __ATOMIC_RELAXED,
                       __HIP_MEMORY_SCOPE_AGENT);

  // ---- last-block-done final reduction (fixed order -> deterministic) ----
  if (tid == 0) {
    const int c = __hip_atomic_fetch_add(&g_ctr, 1, __ATOMIC_ACQ_REL,
                                         __HIP_MEMORY_SCOPE_AGENT);
    slast = (c == nb - 1) ? 1 : 0;
  }
  __syncthreads();
  if (slast) {
    double s = 0.0;
    for (int j = tid; j < nb; j += TPB)
      s += __hip_atomic_load(&g_part[j], __ATOMIC_RELAXED,
                             __HIP_MEMORY_SCOPE_AGENT);
    red[tid] = s;
    __syncthreads();
    for (int k2 = TPB / 2; k2 > 0; k2 >>= 1) {
      if (tid < k2) red[tid] += red[tid + k2];
      __syncthreads();
    }
    if (tid == 0) {
      out[0] = (float)(-red[0] / (double)M);
      __hip_atomic_store(&g_ctr, 0, __ATOMIC_RELAXED,
                         __HIP_MEMORY_SCOPE_AGENT);  // restore for next replay
    }
  }
}

extern "C" void kernel_launch(void* const* d_in, const int* in_sizes, int n_in,
                              void* d_out, int out_size, void* d_ws, size_t ws_size,
                              hipStream_t stream) {
  const float* u   = (const float*)d_in[0];
  const float* v   = (const float*)d_in[1];
  const float* eps = (const float*)d_in[2];
  const float* I   = (const float*)d_in[3];
  const float* W   = (const float*)d_in[4];
  const float* sb  = (const float*)d_in[5];
  const float* sn  = (const float*)d_in[6];
  const float* dd  = (const float*)d_in[7];
  const float* r   = (const float*)d_in[8];
  const int M  = in_sizes[0];
  const int nb = (M + TPB - 1) / TPB;   // 977 for M=250000 (g_part holds 1024)
  hipLaunchKernelGGL(fused_kernel, dim3(nb), dim3(TPB), 0, stream,
                     u, v, eps, I, W, sb, sn, dd, r, (float*)d_out, M, nb);
}